// Round 1
// baseline (256.671 us; speedup 1.0000x reference)
//
#include <hip/hip_runtime.h>
#include <math.h>

#define DIM 96
#define NE 4
#define HH 128
#define WW 128
#define BB 16
#define CHUNK 16
#define NCHUNK (DIM / CHUNK)

// ---------------- Kernel A: per-(b,c) mean pool ----------------
__global__ __launch_bounds__(256) void pool_kernel(const float* __restrict__ x,
                                                   float* __restrict__ pooled) {
    const int bc = blockIdx.x;  // 0..B*C-1
    const float4* p = (const float4*)(x + (size_t)bc * (HH * WW));
    const int t = threadIdx.x;
    float s = 0.f;
#pragma unroll
    for (int k = 0; k < (HH * WW / 4) / 256; ++k) {
        float4 v = p[t + k * 256];
        s += v.x + v.y + v.z + v.w;
    }
#pragma unroll
    for (int off = 32; off; off >>= 1) s += __shfl_down(s, off, 64);
    __shared__ float ls[4];
    if ((t & 63) == 0) ls[t >> 6] = s;
    __syncthreads();
    if (t == 0) pooled[bc] = (ls[0] + ls[1] + ls[2] + ls[3]) * (1.0f / (HH * WW));
}

// ---------------- Kernel B: router (softmax top-1 + gate) ----------------
__global__ void router_kernel(const float* __restrict__ pooled,
                              const float* __restrict__ rw,
                              const float* __restrict__ rb,
                              float* __restrict__ gate, int* __restrict__ sel) {
    const int b = threadIdx.x;
    if (b >= BB) return;
    float logits[NE];
#pragma unroll
    for (int e = 0; e < NE; ++e) {
        float s = rb[e];
        for (int c = 0; c < DIM; ++c) s += pooled[b * DIM + c] * rw[e * DIM + c];
        logits[e] = s;
    }
    float m = logits[0];
    int mi = 0;
#pragma unroll
    for (int e = 1; e < NE; ++e)
        if (logits[e] > m) { m = logits[e]; mi = e; }
    float denom = 0.f;
#pragma unroll
    for (int e = 0; e < NE; ++e) denom += expf(logits[e] - m);
    float w = 1.0f / denom;            // softmax value at argmax
    gate[b] = w / (w + 1e-8f);         // top-k renormalization (k=1)
    sel[b] = mi;
}

// ---------------- Kernel C: fused expert (dw3x3 + GELU + 1x1) ----------------
// One block = one (batch, 2-row strip). 256 threads.
// Channel-chunked: stage x + PW^T + dw weights in LDS, depthwise+GELU to LDS,
// then register-blocked pointwise: thread owns 12 c_out x 8 px accumulators.
__global__ __launch_bounds__(256, 2) void moe_main(
    const float* __restrict__ x, const float* __restrict__ dw_w,
    const float* __restrict__ dw_b, const float* __restrict__ pw_w,
    const float* __restrict__ pw_b, const float* __restrict__ gate,
    const int* __restrict__ sel, float* __restrict__ out) {
    __shared__ float xs[CHUNK][4][WW];        // 32 KB: 4 input rows (incl. halo)
    __shared__ float hs[CHUNK][2 * WW];       // 16 KB: gelu(dw(x)) for 2 rows
    __shared__ float pws[CHUNK][DIM];         // 6 KB: PW^T chunk [ci][co]
    __shared__ float dws[CHUNK][10];          // 9 taps + bias per channel

    const int t = threadIdx.x;
    const int strip = blockIdx.x;  // 0..63
    const int b = blockIdx.y;      // 0..15
    const int r0 = strip * 2;
    const int e = sel[b];
    const float g = gate[b];

    float acc[12][8];
#pragma unroll
    for (int i = 0; i < 12; ++i)
#pragma unroll
        for (int j = 0; j < 8; ++j) acc[i][j] = 0.f;

    const int co_g = t >> 5;  // 0..7  -> owns c_out [co_g*12, +12)
    const int px_g = t & 31;  // 0..31 -> owns px    [px_g*8, +8)
    const int drow = t >> 7, dcol = t & 127;  // depthwise pixel

    for (int ch = 0; ch < NCHUNK; ++ch) {
        const int cb = ch * CHUNK;
        // ---- stage x chunk: 16 ch x 4 rows x 128 cols (float4, coalesced)
#pragma unroll
        for (int k = 0; k < 8; ++k) {
            const int j = t + k * 256;           // 0..2047 float4 slots
            const int col4 = j & 31, row = (j >> 5) & 3, cc = j >> 7;
            const int gr = r0 - 1 + row;
            float4 v = make_float4(0.f, 0.f, 0.f, 0.f);
            if (gr >= 0 && gr < HH)
                v = ((const float4*)x)[(((size_t)(b * DIM + cb + cc)) * HH + gr) * (WW / 4) + col4];
            *(float4*)&xs[cc][row][col4 * 4] = v;
        }
        // ---- stage PW^T chunk
#pragma unroll
        for (int k = 0; k < 6; ++k) {
            const int j = t + k * 256;           // 0..1535
            const int ci = j & 15, co = j >> 4;
            pws[ci][co] = pw_w[(e * DIM + co) * DIM + cb + ci];
        }
        // ---- stage dw weights + bias
        if (t < CHUNK * 10) {
            const int ci = t / 10, q = t % 10;
            dws[ci][q] = (q < 9) ? dw_w[(e * DIM + cb + ci) * 9 + q]
                                 : dw_b[e * DIM + cb + ci];
        }
        __syncthreads();

        // ---- depthwise 3x3 + bias + exact GELU
#pragma unroll
        for (int ci = 0; ci < CHUNK; ++ci) {
            float h = dws[ci][9];
#pragma unroll
            for (int ky = 0; ky < 3; ++ky) {
#pragma unroll
                for (int kx = 0; kx < 3; ++kx) {
                    const int c2 = dcol + kx - 1;
                    if (c2 >= 0 && c2 < WW)
                        h += dws[ci][ky * 3 + kx] * xs[ci][drow + ky][c2];
                }
            }
            hs[ci][t] = 0.5f * h * (1.0f + erff(h * 0.7071067811865475f));
        }
        __syncthreads();

        // ---- pointwise accumulate (register blocked 12x8)
#pragma unroll
        for (int ci = 0; ci < CHUNK; ++ci) {
            const float4 h0 = *(const float4*)&hs[ci][px_g * 8];
            const float4 h1 = *(const float4*)&hs[ci][px_g * 8 + 4];
            const float hv[8] = {h0.x, h0.y, h0.z, h0.w, h1.x, h1.y, h1.z, h1.w};
            const float4 p0 = *(const float4*)&pws[ci][co_g * 12];
            const float4 p1 = *(const float4*)&pws[ci][co_g * 12 + 4];
            const float4 p2 = *(const float4*)&pws[ci][co_g * 12 + 8];
            const float pv[12] = {p0.x, p0.y, p0.z, p0.w, p1.x, p1.y,
                                  p1.z, p1.w, p2.x, p2.y, p2.z, p2.w};
#pragma unroll
            for (int cc = 0; cc < 12; ++cc)
#pragma unroll
                for (int j = 0; j < 8; ++j) acc[cc][j] += pv[cc] * hv[j];
        }
        __syncthreads();
    }

    // ---- epilogue: bias + gate, float4 stores
    const int prow = px_g >> 4;            // 0/1 within strip
    const int pcol = (px_g & 15) * 8;
#pragma unroll
    for (int cc = 0; cc < 12; ++cc) {
        const int co = co_g * 12 + cc;
        const float bias = pw_b[e * DIM + co];
        float o[8];
#pragma unroll
        for (int j = 0; j < 8; ++j) o[j] = (acc[cc][j] + bias) * g;
        float* dst = out + (((size_t)(b * DIM + co)) * HH + (r0 + prow)) * WW + pcol;
        *(float4*)dst = make_float4(o[0], o[1], o[2], o[3]);
        *(float4*)(dst + 4) = make_float4(o[4], o[5], o[6], o[7]);
    }
}

extern "C" void kernel_launch(void* const* d_in, const int* in_sizes, int n_in,
                              void* d_out, int out_size, void* d_ws, size_t ws_size,
                              hipStream_t stream) {
    const float* x    = (const float*)d_in[0];
    const float* dw_w = (const float*)d_in[1];
    const float* dw_b = (const float*)d_in[2];
    const float* pw_w = (const float*)d_in[3];
    const float* pw_b = (const float*)d_in[4];
    const float* rw   = (const float*)d_in[5];
    const float* rb   = (const float*)d_in[6];
    float* out = (float*)d_out;

    float* pooled = (float*)d_ws;              // B*C floats
    float* gate = pooled + BB * DIM;           // B floats
    int* sel = (int*)(gate + BB);              // B ints

    pool_kernel<<<BB * DIM, 256, 0, stream>>>(x, pooled);
    router_kernel<<<1, 64, 0, stream>>>(pooled, rw, rb, gate, sel);
    dim3 grid(HH / 2, BB);
    moe_main<<<grid, 256, 0, stream>>>(x, dw_w, dw_b, pw_w, pw_b, gate, sel, out);
}

// Round 2
// 157.599 us; speedup vs baseline: 1.6286x; 1.6286x over previous
//
#include <hip/hip_runtime.h>
#include <math.h>

#define DIM 96
#define NE 4
#define HH 128
#define WW 128
#define BB 16
#define CK 32            // channels per K-chunk
#define NCH (DIM / CK)   // 3 chunks
#define HPAD 40          // padded K-stride (ushorts) for hs/pwT

typedef __attribute__((ext_vector_type(8))) __bf16 bf16x8;
typedef __attribute__((ext_vector_type(4))) float floatx4;

__device__ __forceinline__ unsigned short f2bf(float f) {
    unsigned u = __builtin_bit_cast(unsigned, f);
    unsigned r = u + 0x7FFFu + ((u >> 16) & 1u);   // RNE
    return (unsigned short)(r >> 16);
}
__device__ __forceinline__ float bf2f(unsigned short s) {
    return __builtin_bit_cast(float, (unsigned)s << 16);
}
__device__ __forceinline__ unsigned pack2(float a, float b) {
    return (unsigned)f2bf(a) | ((unsigned)f2bf(b) << 16);
}

// ---------------- Kernel A: per-(b,c) mean pool ----------------
__global__ __launch_bounds__(256) void pool_kernel(const float* __restrict__ x,
                                                   float* __restrict__ pooled) {
    const int bc = blockIdx.x;
    const float4* p = (const float4*)(x + (size_t)bc * (HH * WW));
    const int t = threadIdx.x;
    float s = 0.f;
#pragma unroll
    for (int k = 0; k < (HH * WW / 4) / 256; ++k) {
        float4 v = p[t + k * 256];
        s += v.x + v.y + v.z + v.w;
    }
#pragma unroll
    for (int off = 32; off; off >>= 1) s += __shfl_down(s, off, 64);
    __shared__ float ls[4];
    if ((t & 63) == 0) ls[t >> 6] = s;
    __syncthreads();
    if (t == 0) pooled[bc] = (ls[0] + ls[1] + ls[2] + ls[3]) * (1.0f / (HH * WW));
}

// ---------------- Kernel B: router ----------------
__global__ void router_kernel(const float* __restrict__ pooled,
                              const float* __restrict__ rw,
                              const float* __restrict__ rb,
                              float* __restrict__ gate, int* __restrict__ sel) {
    const int b = threadIdx.x;
    if (b >= BB) return;
    float logits[NE];
#pragma unroll
    for (int e = 0; e < NE; ++e) {
        float s = rb[e];
        for (int c = 0; c < DIM; ++c) s += pooled[b * DIM + c] * rw[e * DIM + c];
        logits[e] = s;
    }
    float m = logits[0];
    int mi = 0;
#pragma unroll
    for (int e = 1; e < NE; ++e)
        if (logits[e] > m) { m = logits[e]; mi = e; }
    float denom = 0.f;
#pragma unroll
    for (int e = 0; e < NE; ++e) denom += expf(logits[e] - m);
    float w = 1.0f / denom;
    gate[b] = w / (w + 1e-8f);
    sel[b] = mi;
}

// ---------------- Kernel C: fused expert (dw3x3 + GELU + MFMA 1x1) ----------
// Block = (batch, 2-row strip), 256 threads = 4 waves (2 co-halves x 2 px-halves).
// Per 32-channel chunk: stage x(bf16)+pw^T(bf16)+dw coefs -> depthwise+GELU
// (fp32, exact erf) -> hs[px][k] bf16 -> MFMA 16x16x32 accumulate D[co][px].
__global__ __launch_bounds__(256, 2) void moe_main(
    const float* __restrict__ x, const float* __restrict__ dw_w,
    const float* __restrict__ dw_b, const float* __restrict__ pw_w,
    const float* __restrict__ pw_b, const float* __restrict__ gate,
    const int* __restrict__ sel, float* __restrict__ out) {
    __shared__ unsigned short xs[CK][4][WW];      // 32 KB  (bf16 bits)
    __shared__ unsigned short hs[2 * WW][HPAD];   // 20 KB  A-matrix [px][k]
    __shared__ unsigned short pwT[DIM][HPAD];     // 7.5 KB [co][k]
    __shared__ float dwc[CK][10];                 // taps + bias

    const int t = threadIdx.x;
    const int strip = blockIdx.x;   // 0..63
    const int b = blockIdx.y;       // 0..15
    const int r0 = strip * 2;
    const int e = sel[b];
    const float g = gate[b];

    const int lane = t & 63, w = t >> 6;
    const int wm = w & 1, wn = w >> 1;
    const int ln = lane & 15, kg = lane >> 4;
    const int cobase = wm * 48, pxbase = wn * 128;
    const int drow = t >> 7, dcol = t & 127;

    floatx4 acc[3][8];
#pragma unroll
    for (int i = 0; i < 3; ++i)
#pragma unroll
        for (int j = 0; j < 8; ++j) acc[i][j] = (floatx4){0.f, 0.f, 0.f, 0.f};

    for (int ch = 0; ch < NCH; ++ch) {
        const int cb = ch * CK;
        // ---- stage x chunk: 32 ch x 4 rows (halo) x 128 cols, fp32 -> bf16
#pragma unroll
        for (int k = 0; k < 16; ++k) {
            const int j = t + k * 256;              // 0..4095 float4 slots
            const int col4 = j & 31, row = (j >> 5) & 3, cc = j >> 7;
            const int gr = r0 - 1 + row;
            float4 v = make_float4(0.f, 0.f, 0.f, 0.f);
            if (gr >= 0 && gr < HH)
                v = ((const float4*)x)[(((size_t)(b * DIM + cb + cc)) * HH + gr) * (WW / 4) + col4];
            *(uint2*)&xs[cc][row][col4 * 4] = make_uint2(pack2(v.x, v.y), pack2(v.z, v.w));
        }
        // ---- stage pw^T chunk: pw_w[e][co][cb..cb+32)  (row-major, direct)
#pragma unroll
        for (int k = 0; k < 3; ++k) {
            const int j = t + k * 256;              // 0..767
            const int c4 = j & 7, co = j >> 3;
            float4 v = ((const float4*)pw_w)[(size_t)(e * DIM + co) * (DIM / 4) + cb / 4 + c4];
            *(uint2*)&pwT[co][c4 * 4] = make_uint2(pack2(v.x, v.y), pack2(v.z, v.w));
        }
        // ---- stage dw taps + bias
        for (int j = t; j < CK * 10; j += 256) {
            const int ci = j / 10, q = j - ci * 10;
            dwc[ci][q] = (q < 9) ? dw_w[((size_t)e * DIM + cb + ci) * 9 + q]
                                 : dw_b[e * DIM + cb + ci];
        }
        __syncthreads();

        // ---- depthwise 3x3 + bias + exact GELU (fp32), pack pairs into hs
#pragma unroll
        for (int ci = 0; ci < CK; ci += 2) {
            float hv[2];
#pragma unroll
            for (int u = 0; u < 2; ++u) {
                const int c = ci + u;
                float h = dwc[c][9];
#pragma unroll
                for (int ky = 0; ky < 3; ++ky) {
#pragma unroll
                    for (int kx = 0; kx < 3; ++kx) {
                        const int c2 = dcol + kx - 1;
                        if (c2 >= 0 && c2 < WW)
                            h += dwc[c][ky * 3 + kx] * bf2f(xs[c][drow + ky][c2]);
                    }
                }
                hv[u] = 0.5f * h * (1.0f + erff(h * 0.7071067811865475f));
            }
            *(unsigned*)&hs[t][ci] = pack2(hv[0], hv[1]);
        }
        __syncthreads();

        // ---- MFMA: D[co][px] += pwT^T x hs
        bf16x8 af[3], bfr[8];
#pragma unroll
        for (int mf = 0; mf < 3; ++mf)
            af[mf] = *(const bf16x8*)&pwT[cobase + mf * 16 + ln][kg * 8];
#pragma unroll
        for (int nf = 0; nf < 8; ++nf)
            bfr[nf] = *(const bf16x8*)&hs[pxbase + nf * 16 + ln][kg * 8];
#pragma unroll
        for (int mf = 0; mf < 3; ++mf)
#pragma unroll
            for (int nf = 0; nf < 8; ++nf)
                acc[mf][nf] = __builtin_amdgcn_mfma_f32_16x16x32_bf16(
                    af[mf], bfr[nf], acc[mf][nf], 0, 0, 0);
        __syncthreads();
    }

    // ---- epilogue: bias + gate; lanes 0..15 cover 16 consecutive px (64B)
#pragma unroll
    for (int mf = 0; mf < 3; ++mf) {
        const int cox = cobase + mf * 16 + kg * 4;
#pragma unroll
        for (int r = 0; r < 4; ++r) {
            const int co = cox + r;
            const float bias = pw_b[e * DIM + co];
            float* orow = out + ((size_t)(b * DIM + co)) * (HH * WW);
#pragma unroll
            for (int nf = 0; nf < 8; ++nf) {
                const int px = pxbase + nf * 16 + ln;
                orow[(r0 + (px >> 7)) * WW + (px & 127)] = (acc[mf][nf][r] + bias) * g;
            }
        }
    }
}

extern "C" void kernel_launch(void* const* d_in, const int* in_sizes, int n_in,
                              void* d_out, int out_size, void* d_ws, size_t ws_size,
                              hipStream_t stream) {
    const float* x    = (const float*)d_in[0];
    const float* dw_w = (const float*)d_in[1];
    const float* dw_b = (const float*)d_in[2];
    const float* pw_w = (const float*)d_in[3];
    const float* pw_b = (const float*)d_in[4];
    const float* rw   = (const float*)d_in[5];
    const float* rb   = (const float*)d_in[6];
    float* out = (float*)d_out;

    float* pooled = (float*)d_ws;              // B*C floats
    float* gate = pooled + BB * DIM;           // B floats
    int* sel = (int*)(gate + BB);              // B ints

    pool_kernel<<<BB * DIM, 256, 0, stream>>>(x, pooled);
    router_kernel<<<1, 64, 0, stream>>>(pooled, rw, rb, gate, sel);
    dim3 grid(HH / 2, BB);
    moe_main<<<grid, 256, 0, stream>>>(x, dw_w, dw_b, pw_w, pw_b, gate, sel, out);
}

// Round 3
// 110.276 us; speedup vs baseline: 2.3275x; 1.4291x over previous
//
#include <hip/hip_runtime.h>
#include <math.h>

#define DIM 96
#define NE 4
#define HH 128
#define WW 128
#define BB 16
#define KP 24   // padded k-stride (u16) for hs/pwT: 48B row, 16B-aligned for b128

typedef __attribute__((ext_vector_type(8))) __bf16 bf16x8;
typedef __attribute__((ext_vector_type(4))) float floatx4;

__device__ __forceinline__ unsigned short f2bf(float f) {
    unsigned u = __builtin_bit_cast(unsigned, f);
    unsigned r = u + 0x7FFFu + ((u >> 16) & 1u);   // RNE
    return (unsigned short)(r >> 16);
}
__device__ __forceinline__ unsigned pack2(float a, float b) {
    return (unsigned)f2bf(a) | ((unsigned)f2bf(b) << 16);
}

// ---------------- Kernel A: per-(b,c) mean pool ----------------
__global__ __launch_bounds__(256) void pool_kernel(const float* __restrict__ x,
                                                   float* __restrict__ pooled) {
    const int bc = blockIdx.x;
    const float4* p = (const float4*)(x + (size_t)bc * (HH * WW));
    const int t = threadIdx.x;
    float s = 0.f;
#pragma unroll
    for (int k = 0; k < (HH * WW / 4) / 256; ++k) {
        float4 v = p[t + k * 256];
        s += v.x + v.y + v.z + v.w;
    }
#pragma unroll
    for (int off = 32; off; off >>= 1) s += __shfl_down(s, off, 64);
    __shared__ float ls[4];
    if ((t & 63) == 0) ls[t >> 6] = s;
    __syncthreads();
    if (t == 0) pooled[bc] = (ls[0] + ls[1] + ls[2] + ls[3]) * (1.0f / (HH * WW));
}

// ---------------- Kernel B: router ----------------
__global__ void router_kernel(const float* __restrict__ pooled,
                              const float* __restrict__ rw,
                              const float* __restrict__ rb,
                              float* __restrict__ gate, int* __restrict__ sel) {
    const int b = threadIdx.x;
    if (b >= BB) return;
    float logits[NE];
#pragma unroll
    for (int e = 0; e < NE; ++e) {
        float s = rb[e];
        for (int c = 0; c < DIM; ++c) s += pooled[b * DIM + c] * rw[e * DIM + c];
        logits[e] = s;
    }
    float m = logits[0];
    int mi = 0;
#pragma unroll
    for (int e = 1; e < NE; ++e)
        if (logits[e] > m) { m = logits[e]; mi = e; }
    float denom = 0.f;
#pragma unroll
    for (int e = 0; e < NE; ++e) denom += expf(logits[e] - m);
    float w = 1.0f / denom;
    gate[b] = w / (w + 1e-8f);
    sel[b] = mi;
}

// ---------------- Kernel C: fused expert, 1 row per block ----------------
// 256 threads = 4 waves. Depthwise 3x3 + GELU straight from global (coalesced,
// L2/L3-served halo), branchless via clamped indices + 0/1 weight masks.
// hs double-buffer pairs two 16-ch chunks into one K=32 MFMA step.
__global__ __launch_bounds__(256, 4) void moe_main(
    const float* __restrict__ x, const float* __restrict__ dw_w,
    const float* __restrict__ dw_b, const float* __restrict__ pw_w,
    const float* __restrict__ pw_b, const float* __restrict__ gate,
    const int* __restrict__ sel, float* __restrict__ out) {
    __shared__ unsigned short hs[2][WW][KP];     // 12.3 KB [buf][px][klocal]
    __shared__ unsigned short pwT[2][DIM][KP];   // 9.2 KB  [buf][co][klocal]
    __shared__ float dwc[DIM][12];               // 4.6 KB  taps(9)+bias

    const int t = threadIdx.x;
    const int r = blockIdx.x;       // 0..127
    const int b = blockIdx.y;       // 0..15
    const int e = sel[b];
    const float g = gate[b];

    const int lane = t & 63, w = t >> 6;
    const int wm = w & 1, wn = w >> 1;
    const int ln = lane & 15, kg = lane >> 4;
    const int cobase = wm * 48, pxbase = wn * 64;

    const int px = t & 127, half = t >> 7;

    // row/col clamps + masks (branchless SAME padding)
    const int rr0 = (r > 0) ? r - 1 : 0;
    const int rr2 = (r < HH - 1) ? r + 1 : HH - 1;
    const float m0 = (r > 0) ? 1.f : 0.f;
    const float m2 = (r < HH - 1) ? 1.f : 0.f;
    const int cl = (px > 0) ? px - 1 : 0;
    const int cr = (px < WW - 1) ? px + 1 : WW - 1;
    const float mlm = (px > 0) ? 1.f : 0.f;
    const float mrm = (px < WW - 1) ? 1.f : 0.f;
    const float msk0 = m0 * mlm, msk1 = m0, msk2 = m0 * mrm;
    const float msk3 = mlm, msk5 = mrm;
    const float msk6 = m2 * mlm, msk7 = m2, msk8 = m2 * mrm;

    // stage all depthwise taps + bias
    for (int j = t; j < DIM * 12; j += 256) {
        const int c = j / 12, q = j - c * 12;
        float v = 0.f;
        if (q < 9) v = dw_w[((size_t)e * DIM + c) * 9 + q];
        else if (q == 9) v = dw_b[e * DIM + c];
        dwc[c][q] = v;
    }
    __syncthreads();

    floatx4 acc[3][4];
#pragma unroll
    for (int i = 0; i < 3; ++i)
#pragma unroll
        for (int j = 0; j < 4; ++j) acc[i][j] = (floatx4){0.f, 0.f, 0.f, 0.f};

    for (int pair = 0; pair < 3; ++pair) {
#pragma unroll
        for (int sub = 0; sub < 2; ++sub) {
            const int cb = pair * 32 + sub * 16 + half * 8;
            // 8 channels: depthwise + GELU, write bf16 pairs to hs[sub]
#pragma unroll 2
            for (int ii = 0; ii < 4; ++ii) {
                float hv[2];
#pragma unroll
                for (int u = 0; u < 2; ++u) {
                    const int c = cb + ii * 2 + u;
                    const float* pl = x + (size_t)(b * DIM + c) * (HH * WW);
                    const float* p0 = pl + rr0 * WW;
                    const float* p1 = pl + r * WW;
                    const float* p2 = pl + rr2 * WW;
                    const float xv0 = p0[cl], xv1 = p0[px], xv2 = p0[cr];
                    const float xv3 = p1[cl], xv4 = p1[px], xv5 = p1[cr];
                    const float xv6 = p2[cl], xv7 = p2[px], xv8 = p2[cr];
                    const float4 wa = *(const float4*)&dwc[c][0];
                    const float4 wb2 = *(const float4*)&dwc[c][4];
                    const float2 wc2 = *(const float2*)&dwc[c][8];
                    float h = wc2.y;  // bias
                    h += wa.x * msk0 * xv0;
                    h += wa.y * msk1 * xv1;
                    h += wa.z * msk2 * xv2;
                    h += wa.w * msk3 * xv3;
                    h += wb2.x * xv4;
                    h += wb2.y * msk5 * xv5;
                    h += wb2.z * msk6 * xv6;
                    h += wb2.w * msk7 * xv7;
                    h += wc2.x * msk8 * xv8;
                    hv[u] = 0.5f * h * (1.0f + erff(h * 0.7071067811865475f));
                }
                *(unsigned*)&hs[sub][px][half * 8 + ii * 2] = pack2(hv[0], hv[1]);
            }
            if (sub == 0) {
                // stage pw^T for both k-halves of this pair
#pragma unroll
                for (int p = 0; p < 2; ++p)
#pragma unroll
                    for (int i2 = 0; i2 < 3; ++i2) {
                        const int u = i2 * 256 + t;      // 0..767
                        const int co = u >> 3, kk = (u & 7) * 2;
                        const float2 v = *(const float2*)(pw_w +
                            ((size_t)e * DIM + co) * DIM + pair * 32 + p * 16 + kk);
                        *(unsigned*)&pwT[p][co][kk] = pack2(v.x, v.y);
                    }
            }
        }
        __syncthreads();

        // MFMA: K=32 over the two buffers
        const int bufi = kg >> 1, klo = (kg & 1) * 8;
        bf16x8 af[3], bfr[4];
#pragma unroll
        for (int mf = 0; mf < 3; ++mf)
            af[mf] = *(const bf16x8*)&pwT[bufi][cobase + mf * 16 + ln][klo];
#pragma unroll
        for (int nf = 0; nf < 4; ++nf)
            bfr[nf] = *(const bf16x8*)&hs[bufi][pxbase + nf * 16 + ln][klo];
#pragma unroll
        for (int mf = 0; mf < 3; ++mf)
#pragma unroll
            for (int nf = 0; nf < 4; ++nf)
                acc[mf][nf] = __builtin_amdgcn_mfma_f32_16x16x32_bf16(
                    af[mf], bfr[nf], acc[mf][nf], 0, 0, 0);
        __syncthreads();
    }

    // epilogue: bias + gate, coalesced 64B segments
#pragma unroll
    for (int mf = 0; mf < 3; ++mf) {
#pragma unroll
        for (int rr = 0; rr < 4; ++rr) {
            const int co = cobase + mf * 16 + kg * 4 + rr;
            const float bias = pw_b[e * DIM + co];
            float* orow = out + ((size_t)(b * DIM + co) * HH + r) * WW;
#pragma unroll
            for (int nf = 0; nf < 4; ++nf)
                orow[pxbase + nf * 16 + ln] = (acc[mf][nf][rr] + bias) * g;
        }
    }
}

extern "C" void kernel_launch(void* const* d_in, const int* in_sizes, int n_in,
                              void* d_out, int out_size, void* d_ws, size_t ws_size,
                              hipStream_t stream) {
    const float* x    = (const float*)d_in[0];
    const float* dw_w = (const float*)d_in[1];
    const float* dw_b = (const float*)d_in[2];
    const float* pw_w = (const float*)d_in[3];
    const float* pw_b = (const float*)d_in[4];
    const float* rw   = (const float*)d_in[5];
    const float* rb   = (const float*)d_in[6];
    float* out = (float*)d_out;

    float* pooled = (float*)d_ws;              // B*C floats
    float* gate = pooled + BB * DIM;           // B floats
    int* sel = (int*)(gate + BB);              // B ints

    pool_kernel<<<BB * DIM, 256, 0, stream>>>(x, pooled);
    router_kernel<<<1, 64, 0, stream>>>(pooled, rw, rb, gate, sel);
    dim3 grid(HH, BB);
    moe_main<<<grid, 256, 0, stream>>>(x, dw_w, dw_b, pw_w, pw_b, gate, sel, out);
}